// Round 3
// baseline (682.946 us; speedup 1.0000x reference)
//
#include <hip/hip_runtime.h>
#include <math.h>

#define NB 8
#define NS 2048
#define NF 32
#define ND 256
#define NTOK (NB * NS)

// ---------- DPP wave-sum (64 lanes, result lands in lane 63) ----------
template <int CTRL, int RM>
__device__ __forceinline__ float dpp_step(float v) {
    int t = __builtin_amdgcn_update_dpp(0, __float_as_int(v), CTRL, RM, 0xf, true);
    return v + __int_as_float(t);
}
__device__ __forceinline__ float wave_sum63(float v) {
    v = dpp_step<0x111, 0xf>(v);  // row_shr:1
    v = dpp_step<0x112, 0xf>(v);  // row_shr:2
    v = dpp_step<0x114, 0xf>(v);  // row_shr:4
    v = dpp_step<0x118, 0xf>(v);  // row_shr:8
    v = dpp_step<0x142, 0xa>(v);  // row_bcast:15 -> rows 1,3
    v = dpp_step<0x143, 0xc>(v);  // row_bcast:31 -> rows 2,3
    return v;                     // lane 63 holds the total
}
__device__ __forceinline__ float lane63(float v) {
    return __int_as_float(__builtin_amdgcn_readlane(__float_as_int(v), 63));
}

// (1 + erf(u)) via A&S 7.1.25 (3-term, |err| <= 2.5e-5), branchless
__device__ __forceinline__ float one_plus_erf(float u) {
    const float a = fabsf(u);
    const float t = __builtin_amdgcn_rcpf(fmaf(0.47047f, a, 1.0f));
    const float poly = t * fmaf(t, fmaf(t, 0.7478556f, -0.0958798f), 0.3480242f);
    const float e = exp2f(-1.4426950408889634f * a * a);
    const float pe = poly * e;                      // = 1 - erf(a)
    return (u >= 0.0f) ? (2.0f - pe) : pe;          // 1 + erf(u)
}

// ---------- per-f row statistics of W,b (token-independent) ----------
__global__ void vsn_stats(const float* __restrict__ W, const float* __restrict__ bias,
                          float* __restrict__ stats) {
    const int f = blockIdx.x;       // 32 blocks
    const int lane = threadIdx.x;   // 64 threads
    const float4 w4 = *(const float4*)(W + f * ND + (lane << 2));
    const float4 b4 = *(const float4*)(bias + f * ND + (lane << 2));
    float sw  = (w4.x + w4.y) + (w4.z + w4.w);
    float sb  = (b4.x + b4.y) + (b4.z + b4.w);
    float sww = fmaf(w4.x, w4.x, fmaf(w4.y, w4.y, fmaf(w4.z, w4.z, w4.w * w4.w)));
    float swb = fmaf(w4.x, b4.x, fmaf(w4.y, b4.y, fmaf(w4.z, b4.z, w4.w * b4.w)));
    float sbb = fmaf(b4.x, b4.x, fmaf(b4.y, b4.y, fmaf(b4.z, b4.z, b4.w * b4.w)));
#pragma unroll
    for (int m = 32; m >= 1; m >>= 1) {
        sw += __shfl_xor(sw, m);  sb += __shfl_xor(sb, m);
        sww += __shfl_xor(sww, m); swb += __shfl_xor(swb, m); sbb += __shfl_xor(sbb, m);
    }
    if (lane == 0) {
        const float inv_d = 1.0f / ND;
        stats[f]        = sw * inv_d;
        stats[32 + f]   = sb * inv_d;
        stats[64 + f]   = sww * inv_d;
        stats[96 + f]   = swb * inv_d;
        stats[128 + f]  = sbb * inv_d;
    }
}

// ---------- main kernel: one wave per token, lane l owns d=4l..4l+3 ----------
// Online-softmax fusion: no z array, no second pass. den/S accumulated with
// e^{s_f} (no max subtraction; scores are O(1) for this data, far from fp32
// overflow), normalized once at the end. Mathematically identical to softmax.
__global__ __launch_bounds__(256, 4) void vsn_kernel(
    const float* __restrict__ x,      // [NTOK, NF]
    const float* __restrict__ W,      // [NF, ND]
    const float* __restrict__ bias,   // [NF, ND]
    const float* __restrict__ stats,  // [5, NF] from vsn_stats
    const float* __restrict__ ln1g,
    const float* __restrict__ ln1b,
    const float* __restrict__ scw,
    const float* __restrict__ scb,
    const float* __restrict__ outg,
    const float* __restrict__ outb,
    float* __restrict__ out,          // [NTOK, ND]
    float* __restrict__ wout)         // [NTOK, NF]
{
    const int lane = threadIdx.x & 63;
    const int wid  = threadIdx.x >> 6;
    const int tok  = (blockIdx.x << 2) | wid;
    const int d0   = lane << 2;
    const int fl   = lane & 31;

    constexpr float inv_d = 1.0f / 256.0f;
    constexpr float c = 0.70710678118654752440f;   // 1/sqrt(2)
    constexpr float LOG2E = 1.4426950408889634f;

    const float xv = x[tok * NF + fl];

    // closed-form LN1 stats for f = fl (token-dependent, no reduction)
    const float mu_l  = fmaf(xv, stats[fl], stats[32 + fl]);
    const float ez2   = fmaf(xv * xv, stats[64 + fl],
                             fmaf(xv + xv, stats[96 + fl], stats[128 + fl]));
    const float var_l = fmaf(-mu_l, mu_l, ez2);
    const float rsc_l = rsqrtf(var_l + 1e-5f) * c;

    const float4 g4 = *(const float4*)(ln1g + d0);
    float4 bc4 = *(const float4*)(ln1b + d0);
    bc4.x *= c; bc4.y *= c; bc4.z *= c; bc4.w *= c;
    const float4 sw4 = *(const float4*)(scw + d0);
    const float sbv = scb[0];

    float s0 = 0.f, s1 = 0.f, s2 = 0.f, s3 = 0.f;  // sum_f e_f * z[f][d]
    float den = 0.f;                                // sum_f e_f
    float epark = 0.f;                              // lane f parks e_f

#pragma unroll
    for (int f = 0; f < NF; ++f) {
        const float xf  = __shfl(xv, f);
        const float mu  = __shfl(mu_l, f);
        const float rsc = __shfl(rsc_l, f);
        const float4 w4 = *(const float4*)(W + f * ND + d0);
        const float4 c4 = *(const float4*)(bias + f * ND + d0);
        const float z0 = fmaf(xf, w4.x, c4.x);
        const float z1 = fmaf(xf, w4.y, c4.y);
        const float z2 = fmaf(xf, w4.z, c4.z);
        const float z3 = fmaf(xf, w4.w, c4.w);

        // u = LN(z)/sqrt2 with affine folded
        const float u0 = fmaf((z0 - mu) * rsc, g4.x, bc4.x);
        const float u1 = fmaf((z1 - mu) * rsc, g4.y, bc4.y);
        const float u2 = fmaf((z2 - mu) * rsc, g4.z, bc4.z);
        const float u3 = fmaf((z3 - mu) * rsc, g4.w, bc4.w);

        // gelu(n)*scw = (1/sqrt2)*u*(1+erf(u))*scw ; fold 1/sqrt2 at the end
        float dp;
        dp = (u0 * one_plus_erf(u0)) * sw4.x;
        dp = fmaf(u1 * one_plus_erf(u1), sw4.y, dp);
        dp = fmaf(u2 * one_plus_erf(u2), sw4.z, dp);
        dp = fmaf(u3 * one_plus_erf(u3), sw4.w, dp);

        const float sf = fmaf(lane63(wave_sum63(dp)), c, sbv);  // wave-uniform
        const float e  = exp2f(LOG2E * sf);

        den += e;
        s0 = fmaf(e, z0, s0);
        s1 = fmaf(e, z1, s1);
        s2 = fmaf(e, z2, s2);
        s3 = fmaf(e, z3, s3);
        if (lane == f) epark = e;
    }

    const float invden = __builtin_amdgcn_rcpf(den);

    // selected[d] = S[d] / den ; then final LN over selected
    const float v0 = s0 * invden, v1 = s1 * invden, v2 = s2 * invden, v3 = s3 * invden;

    const float su = lane63(wave_sum63((v0 + v1) + (v2 + v3)));
    const float qu = lane63(wave_sum63(
        fmaf(v0, v0, fmaf(v1, v1, fmaf(v2, v2, v3 * v3)))));
    const float mu  = __int_as_float(__builtin_amdgcn_readlane(__float_as_int(su), 63)) * inv_d;
    const float var = fmaf(-mu, mu, qu * inv_d);
    const float rs  = rsqrtf(var + 1e-5f);

    const float4 og4 = *(const float4*)(outg + d0);
    const float4 ob4 = *(const float4*)(outb + d0);
    float4 o;
    o.x = fmaf((v0 - mu) * rs, og4.x, ob4.x);
    o.y = fmaf((v1 - mu) * rs, og4.y, ob4.y);
    o.z = fmaf((v2 - mu) * rs, og4.z, ob4.z);
    o.w = fmaf((v3 - mu) * rs, og4.w, ob4.w);
    *(float4*)(out + tok * ND + d0) = o;

    if (lane < NF) wout[tok * NF + lane] = epark * invden;
}

extern "C" void kernel_launch(void* const* d_in, const int* in_sizes, int n_in,
                              void* d_out, int out_size, void* d_ws, size_t ws_size,
                              hipStream_t stream) {
    const float* x    = (const float*)d_in[0];
    const float* W    = (const float*)d_in[1];
    const float* bias = (const float*)d_in[2];
    const float* ln1g = (const float*)d_in[3];
    const float* ln1b = (const float*)d_in[4];
    const float* scw  = (const float*)d_in[5];
    const float* scb  = (const float*)d_in[6];
    const float* outg = (const float*)d_in[7];
    const float* outb = (const float*)d_in[8];

    float* stats = (float*)d_ws;                 // 5*32 floats
    float* out   = (float*)d_out;                // [NTOK, ND]
    float* wout  = out + (size_t)NTOK * ND;      // [NTOK, NF]

    hipLaunchKernelGGL(vsn_stats, dim3(NF), dim3(64), 0, stream, W, bias, stats);
    hipLaunchKernelGGL(vsn_kernel, dim3(NTOK / 4), dim3(256), 0, stream,
                       x, W, bias, stats, ln1g, ln1b, scw, scb, outg, outb, out, wout);
}

// Round 4
// 116.763 us; speedup vs baseline: 5.8490x; 5.8490x over previous
//
#include <hip/hip_runtime.h>
#include <math.h>

#define NB 8
#define NS 2048
#define NF 32
#define ND 256
#define NTOK (NB * NS)

// ---------- DPP wave-sum (64 lanes, result lands in lane 63) ----------
template <int CTRL, int RM>
__device__ __forceinline__ float dpp_step(float v) {
    int t = __builtin_amdgcn_update_dpp(0, __float_as_int(v), CTRL, RM, 0xf, true);
    return v + __int_as_float(t);
}
__device__ __forceinline__ float wave_sum63(float v) {
    v = dpp_step<0x111, 0xf>(v);  // row_shr:1
    v = dpp_step<0x112, 0xf>(v);  // row_shr:2
    v = dpp_step<0x114, 0xf>(v);  // row_shr:4
    v = dpp_step<0x118, 0xf>(v);  // row_shr:8
    v = dpp_step<0x142, 0xa>(v);  // row_bcast:15 -> rows 1,3
    v = dpp_step<0x143, 0xc>(v);  // row_bcast:31 -> rows 2,3
    return v;                     // lane 63 holds the total
}
__device__ __forceinline__ float lane63(float v) {
    return __int_as_float(__builtin_amdgcn_readlane(__float_as_int(v), 63));
}

// (1 + erf(u)) via A&S 7.1.25 (3-term, |err| <= 2.5e-5), branchless
__device__ __forceinline__ float one_plus_erf(float u) {
    const float a = fabsf(u);
    const float t = __builtin_amdgcn_rcpf(fmaf(0.47047f, a, 1.0f));
    const float poly = t * fmaf(t, fmaf(t, 0.7478556f, -0.0958798f), 0.3480242f);
    const float e = exp2f(-1.4426950408889634f * a * a);
    const float pe = poly * e;                      // = 1 - erf(a)
    return (u >= 0.0f) ? (2.0f - pe) : pe;          // 1 + erf(u)
}

// ---------- per-f row statistics of W,b (token-independent) ----------
__global__ void vsn_stats(const float* __restrict__ W, const float* __restrict__ bias,
                          float* __restrict__ stats) {
    const int f = blockIdx.x;       // 32 blocks
    const int lane = threadIdx.x;   // 64 threads
    const float4 w4 = *(const float4*)(W + f * ND + (lane << 2));
    const float4 b4 = *(const float4*)(bias + f * ND + (lane << 2));
    float sw  = (w4.x + w4.y) + (w4.z + w4.w);
    float sb  = (b4.x + b4.y) + (b4.z + b4.w);
    float sww = fmaf(w4.x, w4.x, fmaf(w4.y, w4.y, fmaf(w4.z, w4.z, w4.w * w4.w)));
    float swb = fmaf(w4.x, b4.x, fmaf(w4.y, b4.y, fmaf(w4.z, b4.z, w4.w * b4.w)));
    float sbb = fmaf(b4.x, b4.x, fmaf(b4.y, b4.y, fmaf(b4.z, b4.z, b4.w * b4.w)));
#pragma unroll
    for (int m = 32; m >= 1; m >>= 1) {
        sw += __shfl_xor(sw, m);  sb += __shfl_xor(sb, m);
        sww += __shfl_xor(sww, m); swb += __shfl_xor(swb, m); sbb += __shfl_xor(sbb, m);
    }
    if (lane == 0) {
        const float inv_d = 1.0f / ND;
        stats[f]        = sw * inv_d;
        stats[32 + f]   = sb * inv_d;
        stats[64 + f]   = sww * inv_d;
        stats[96 + f]   = swb * inv_d;
        stats[128 + f]  = sbb * inv_d;
    }
}

// ---------- main kernel: one wave per token, lane l owns d=4l..4l+3 ----------
// Online-softmax fusion (no z array, no second pass). Partial unroll (2) keeps
// only ~2 iterations of loads in flight -> no spill, small VGPR footprint,
// high occupancy; TLP hides erf/trans latency.
__global__ __launch_bounds__(256, 4) void vsn_kernel(
    const float* __restrict__ x,      // [NTOK, NF]
    const float* __restrict__ W,      // [NF, ND]
    const float* __restrict__ bias,   // [NF, ND]
    const float* __restrict__ stats,  // [5, NF] from vsn_stats
    const float* __restrict__ ln1g,
    const float* __restrict__ ln1b,
    const float* __restrict__ scw,
    const float* __restrict__ scb,
    const float* __restrict__ outg,
    const float* __restrict__ outb,
    float* __restrict__ out,          // [NTOK, ND]
    float* __restrict__ wout)         // [NTOK, NF]
{
    const int lane = threadIdx.x & 63;
    const int wid  = threadIdx.x >> 6;
    const int tok  = (blockIdx.x << 2) | wid;
    const int d0   = lane << 2;
    const int fl   = lane & 31;

    constexpr float inv_d = 1.0f / 256.0f;
    constexpr float c = 0.70710678118654752440f;   // 1/sqrt(2)
    constexpr float LOG2E = 1.4426950408889634f;

    const float xv = x[tok * NF + fl];

    // closed-form LN1 stats for f = fl (token-dependent, no reduction)
    const float mu_l  = fmaf(xv, stats[fl], stats[32 + fl]);
    const float ez2   = fmaf(xv * xv, stats[64 + fl],
                             fmaf(xv + xv, stats[96 + fl], stats[128 + fl]));
    const float var_l = fmaf(-mu_l, mu_l, ez2);
    const float rsc_l = rsqrtf(var_l + 1e-5f) * c;

    const float4 g4 = *(const float4*)(ln1g + d0);
    float4 bc4 = *(const float4*)(ln1b + d0);
    bc4.x *= c; bc4.y *= c; bc4.z *= c; bc4.w *= c;
    const float4 sw4 = *(const float4*)(scw + d0);
    const float sbv = scb[0];

    float s0 = 0.f, s1 = 0.f, s2 = 0.f, s3 = 0.f;  // sum_f e_f * z[f][d]
    float den = 0.f;                                // sum_f e_f
    float epark = 0.f;                              // lane f parks e_f

#pragma unroll 2
    for (int f = 0; f < NF; ++f) {
        const float xf  = __shfl(xv, f);            // runtime lane -> ds_bpermute
        const float mu  = __shfl(mu_l, f);
        const float rsc = __shfl(rsc_l, f);
        const float4 w4 = *(const float4*)(W + f * ND + d0);
        const float4 c4 = *(const float4*)(bias + f * ND + d0);
        const float z0 = fmaf(xf, w4.x, c4.x);
        const float z1 = fmaf(xf, w4.y, c4.y);
        const float z2 = fmaf(xf, w4.z, c4.z);
        const float z3 = fmaf(xf, w4.w, c4.w);

        // u = LN(z)/sqrt2 with affine folded
        const float u0 = fmaf((z0 - mu) * rsc, g4.x, bc4.x);
        const float u1 = fmaf((z1 - mu) * rsc, g4.y, bc4.y);
        const float u2 = fmaf((z2 - mu) * rsc, g4.z, bc4.z);
        const float u3 = fmaf((z3 - mu) * rsc, g4.w, bc4.w);

        // gelu(n)*scw = (1/sqrt2)*u*(1+erf(u))*scw ; 1/sqrt2 folded at the end
        float dp;
        dp = (u0 * one_plus_erf(u0)) * sw4.x;
        dp = fmaf(u1 * one_plus_erf(u1), sw4.y, dp);
        dp = fmaf(u2 * one_plus_erf(u2), sw4.z, dp);
        dp = fmaf(u3 * one_plus_erf(u3), sw4.w, dp);

        const float sf = fmaf(lane63(wave_sum63(dp)), c, sbv);  // wave-uniform
        const float e  = exp2f(LOG2E * sf);

        den += e;
        s0 = fmaf(e, z0, s0);
        s1 = fmaf(e, z1, s1);
        s2 = fmaf(e, z2, s2);
        s3 = fmaf(e, z3, s3);
        if (lane == f) epark = e;
    }

    const float invden = __builtin_amdgcn_rcpf(den);

    // selected[d] = S[d] / den ; then final LN over selected
    const float v0 = s0 * invden, v1 = s1 * invden, v2 = s2 * invden, v3 = s3 * invden;

    const float su = lane63(wave_sum63((v0 + v1) + (v2 + v3)));
    const float qu = lane63(wave_sum63(
        fmaf(v0, v0, fmaf(v1, v1, fmaf(v2, v2, v3 * v3)))));
    const float mu  = su * inv_d;
    const float var = fmaf(-mu, mu, qu * inv_d);
    const float rs  = rsqrtf(var + 1e-5f);

    const float4 og4 = *(const float4*)(outg + d0);
    const float4 ob4 = *(const float4*)(outb + d0);
    float4 o;
    o.x = fmaf((v0 - mu) * rs, og4.x, ob4.x);
    o.y = fmaf((v1 - mu) * rs, og4.y, ob4.y);
    o.z = fmaf((v2 - mu) * rs, og4.z, ob4.z);
    o.w = fmaf((v3 - mu) * rs, og4.w, ob4.w);
    *(float4*)(out + tok * ND + d0) = o;

    if (lane < NF) wout[tok * NF + lane] = epark * invden;
}

extern "C" void kernel_launch(void* const* d_in, const int* in_sizes, int n_in,
                              void* d_out, int out_size, void* d_ws, size_t ws_size,
                              hipStream_t stream) {
    const float* x    = (const float*)d_in[0];
    const float* W    = (const float*)d_in[1];
    const float* bias = (const float*)d_in[2];
    const float* ln1g = (const float*)d_in[3];
    const float* ln1b = (const float*)d_in[4];
    const float* scw  = (const float*)d_in[5];
    const float* scb  = (const float*)d_in[6];
    const float* outg = (const float*)d_in[7];
    const float* outb = (const float*)d_in[8];

    float* stats = (float*)d_ws;                 // 5*32 floats
    float* out   = (float*)d_out;                // [NTOK, ND]
    float* wout  = out + (size_t)NTOK * ND;      // [NTOK, NF]

    hipLaunchKernelGGL(vsn_stats, dim3(NF), dim3(64), 0, stream, W, bias, stats);
    hipLaunchKernelGGL(vsn_kernel, dim3(NTOK / 4), dim3(256), 0, stream,
                       x, W, bias, stats, ln1g, ln1b, scw, scb, outg, outb, out, wout);
}

// Round 6
// 92.251 us; speedup vs baseline: 7.4032x; 1.2657x over previous
//
#include <hip/hip_runtime.h>
#include <math.h>

#define NB 8
#define NS 2048
#define NF 32
#define ND 256
#define NTOK (NB * NS)

typedef float v2 __attribute__((ext_vector_type(2)));

// ---------- DPP wave-sum (64 lanes, result lands in lane 63) ----------
template <int CTRL, int RM>
__device__ __forceinline__ float dpp_step(float v) {
    int t = __builtin_amdgcn_update_dpp(0, __float_as_int(v), CTRL, RM, 0xf, true);
    return v + __int_as_float(t);
}
__device__ __forceinline__ float wave_sum63(float v) {
    v = dpp_step<0x111, 0xf>(v);  // row_shr:1
    v = dpp_step<0x112, 0xf>(v);  // row_shr:2
    v = dpp_step<0x114, 0xf>(v);  // row_shr:4
    v = dpp_step<0x118, 0xf>(v);  // row_shr:8
    v = dpp_step<0x142, 0xa>(v);  // row_bcast:15 -> rows 1,3
    v = dpp_step<0x143, 0xc>(v);  // row_bcast:31 -> rows 2,3
    return v;
}
__device__ __forceinline__ float lane63(float v) {
    return __int_as_float(__builtin_amdgcn_readlane(__float_as_int(v), 63));
}
// wave-uniform broadcast from lane (SGPR lane index ok)
__device__ __forceinline__ float rl(float v, int lane) {
    return __int_as_float(__builtin_amdgcn_readlane(__float_as_int(v), lane));
}

// ---------- per-f row statistics of W,b (token-independent) ----------
__global__ void vsn_stats(const float* __restrict__ W, const float* __restrict__ bias,
                          float* __restrict__ stats) {
    const int f = blockIdx.x;
    const int lane = threadIdx.x;
    const float4 w4 = *(const float4*)(W + f * ND + (lane << 2));
    const float4 b4 = *(const float4*)(bias + f * ND + (lane << 2));
    float sw  = (w4.x + w4.y) + (w4.z + w4.w);
    float sb  = (b4.x + b4.y) + (b4.z + b4.w);
    float sww = fmaf(w4.x, w4.x, fmaf(w4.y, w4.y, fmaf(w4.z, w4.z, w4.w * w4.w)));
    float swb = fmaf(w4.x, b4.x, fmaf(w4.y, b4.y, fmaf(w4.z, b4.z, w4.w * b4.w)));
    float sbb = fmaf(b4.x, b4.x, fmaf(b4.y, b4.y, fmaf(b4.z, b4.z, b4.w * b4.w)));
#pragma unroll
    for (int m = 32; m >= 1; m >>= 1) {
        sw += __shfl_xor(sw, m);  sb += __shfl_xor(sb, m);
        sww += __shfl_xor(sww, m); swb += __shfl_xor(swb, m); sbb += __shfl_xor(sbb, m);
    }
    if (lane == 0) {
        const float inv_d = 1.0f / ND;
        stats[f]        = sw * inv_d;
        stats[32 + f]   = sb * inv_d;
        stats[64 + f]   = sww * inv_d;
        stats[96 + f]   = swb * inv_d;
        stats[128 + f]  = sbb * inv_d;
    }
}

// ---------- main kernel: one wave per token, lane l owns d = 4l..4l+3 ----------
// Online-softmax fusion; tanh-form gelu (|err| ~3e-4, branchless, clean
// saturation); readlane (SGPR) broadcasts; element math on float2 vectors so
// the backend may form v_pk_*_f32 (correct either way). Partial unroll 2
// bounds load hoisting (no spill).
__global__ __launch_bounds__(256, 4) void vsn_kernel(
    const float* __restrict__ x,
    const float* __restrict__ W,
    const float* __restrict__ bias,
    const float* __restrict__ stats,
    const float* __restrict__ ln1g,
    const float* __restrict__ ln1b,
    const float* __restrict__ scw,
    const float* __restrict__ scb,
    const float* __restrict__ outg,
    const float* __restrict__ outb,
    float* __restrict__ out,
    float* __restrict__ wout)
{
    const int lane = threadIdx.x & 63;
    const int wid  = threadIdx.x >> 6;
    const int tok  = (blockIdx.x << 2) | wid;
    const int d0   = lane << 2;
    const int fl   = lane & 31;

    constexpr float inv_d = 1.0f / 256.0f;
    constexpr float LOG2E = 1.4426950408889634f;
    // tanh-gelu: earg = n*(A + B*n^2); A = 2*log2(e)*sqrt(2/pi), B = A*0.044715
    constexpr float GA = 2.3022082062f;
    constexpr float GB = 0.1029432397f;

    const float xv = x[tok * NF + fl];

    // closed-form LN1 stats for f = fl (no cross-lane reduction)
    const float mu_l  = fmaf(xv, stats[fl], stats[32 + fl]);
    const float ez2   = fmaf(xv * xv, stats[64 + fl],
                             fmaf(xv + xv, stats[96 + fl], stats[128 + fl]));
    const float var_l = fmaf(-mu_l, mu_l, ez2);
    const float rs_l  = rsqrtf(var_l + 1e-5f);

    const float4 g4f  = *(const float4*)(ln1g + d0);
    const float4 b4f  = *(const float4*)(ln1b + d0);
    const float4 sw4f = *(const float4*)(scw + d0);
    const float sbv = scb[0];

    const v2 g01 = {g4f.x, g4f.y},  g23 = {g4f.z, g4f.w};
    const v2 b01 = {b4f.x, b4f.y},  b23 = {b4f.z, b4f.w};
    const v2 q01 = {sw4f.x, sw4f.y}, q23 = {sw4f.z, sw4f.w};

    v2 s01 = {0.f, 0.f}, s23 = {0.f, 0.f};   // sum_f e_f * z[f][d]
    float den = 0.f;
    float epark = 0.f;

#pragma unroll 2
    for (int f = 0; f < NF; ++f) {
        const float xf = rl(xv, f);
        const float mu = rl(mu_l, f);
        const float rs = rl(rs_l, f);
        const v2 xf2 = {xf, xf};
        const v2 mu2 = {mu, mu};
        const v2 rs2 = {rs, rs};

        const float4 w4f = *(const float4*)(W + f * ND + d0);
        const float4 c4f = *(const float4*)(bias + f * ND + d0);
        const v2 w01 = {w4f.x, w4f.y}, w23 = {w4f.z, w4f.w};
        const v2 c01 = {c4f.x, c4f.y}, c23 = {c4f.z, c4f.w};

        const v2 z01 = xf2 * w01 + c01;
        const v2 z23 = xf2 * w23 + c23;

        // n = (z - mu)*rs * g + b
        const v2 n01 = ((z01 - mu2) * rs2) * g01 + b01;
        const v2 n23 = ((z23 - mu2) * rs2) * g23 + b23;

        // gelu(n) = n*(1 - r), r = 1/(1 + exp2(n*(GA + GB*n^2)))
        const v2 GA2 = {GA, GA}, GB2 = {GB, GB};
        const v2 ea01 = n01 * (GB2 * (n01 * n01) + GA2);
        const v2 ea23 = n23 * (GB2 * (n23 * n23) + GA2);
        v2 r01, r23;
        r01.x = __builtin_amdgcn_rcpf(exp2f(ea01.x) + 1.0f);
        r01.y = __builtin_amdgcn_rcpf(exp2f(ea01.y) + 1.0f);
        r23.x = __builtin_amdgcn_rcpf(exp2f(ea23.x) + 1.0f);
        r23.y = __builtin_amdgcn_rcpf(exp2f(ea23.y) + 1.0f);
        const v2 h01 = n01 - n01 * r01;
        const v2 h23 = n23 - n23 * r23;

        v2 dp2 = h01 * q01;
        dp2 = h23 * q23 + dp2;

        const float sf = lane63(wave_sum63(dp2.x + dp2.y)) + sbv;
        const float e  = exp2f(LOG2E * sf);
        const v2 e2 = {e, e};

        den += e;
        s01 = e2 * z01 + s01;
        s23 = e2 * z23 + s23;
        if (lane == f) epark = e;
    }

    const float invden = __builtin_amdgcn_rcpf(den);

    // selected[d] = S[d]/den ; final LN over selected
    const float v0 = s01.x * invden, v1 = s01.y * invden;
    const float v2e = s23.x * invden, v3 = s23.y * invden;

    const float su = lane63(wave_sum63((v0 + v1) + (v2e + v3)));
    const float qu = lane63(wave_sum63(
        fmaf(v0, v0, fmaf(v1, v1, fmaf(v2e, v2e, v3 * v3)))));
    const float mu  = su * inv_d;
    const float var = fmaf(-mu, mu, qu * inv_d);
    const float rs  = rsqrtf(var + 1e-5f);

    const float4 og4 = *(const float4*)(outg + d0);
    const float4 ob4 = *(const float4*)(outb + d0);
    float4 o;
    o.x = fmaf((v0 - mu) * rs, og4.x, ob4.x);
    o.y = fmaf((v1 - mu) * rs, og4.y, ob4.y);
    o.z = fmaf((v2e - mu) * rs, og4.z, ob4.z);
    o.w = fmaf((v3 - mu) * rs, og4.w, ob4.w);
    *(float4*)(out + tok * ND + d0) = o;

    if (lane < NF) wout[tok * NF + lane] = epark * invden;
}

extern "C" void kernel_launch(void* const* d_in, const int* in_sizes, int n_in,
                              void* d_out, int out_size, void* d_ws, size_t ws_size,
                              hipStream_t stream) {
    const float* x    = (const float*)d_in[0];
    const float* W    = (const float*)d_in[1];
    const float* bias = (const float*)d_in[2];
    const float* ln1g = (const float*)d_in[3];
    const float* ln1b = (const float*)d_in[4];
    const float* scw  = (const float*)d_in[5];
    const float* scb  = (const float*)d_in[6];
    const float* outg = (const float*)d_in[7];
    const float* outb = (const float*)d_in[8];

    float* stats = (float*)d_ws;                 // 5*32 floats
    float* out   = (float*)d_out;                // [NTOK, ND]
    float* wout  = out + (size_t)NTOK * ND;      // [NTOK, NF]

    hipLaunchKernelGGL(vsn_stats, dim3(NF), dim3(64), 0, stream, W, bias, stats);
    hipLaunchKernelGGL(vsn_kernel, dim3(NTOK / 4), dim3(256), 0, stream,
                       x, W, bias, stats, ln1g, ln1b, scw, scb, outg, outb, out, wout);
}

// Round 7
// 77.068 us; speedup vs baseline: 8.8616x; 1.1970x over previous
//
#include <hip/hip_runtime.h>
#include <math.h>

#define NB 8
#define NS 2048
#define NF 32
#define ND 256
#define NTOK (NB * NS)

typedef float v2 __attribute__((ext_vector_type(2)));

#if __has_builtin(__builtin_amdgcn_exp2f)
#define EXP2(x) __builtin_amdgcn_exp2f(x)
#else
#define EXP2(x) exp2f(x)
#endif

// ---------- DPP wave-sum (64 lanes, result lands in lane 63) ----------
template <int CTRL, int RM>
__device__ __forceinline__ float dpp_step(float v) {
    int t = __builtin_amdgcn_update_dpp(0, __float_as_int(v), CTRL, RM, 0xf, true);
    return v + __int_as_float(t);
}
__device__ __forceinline__ float wave_sum63(float v) {
    v = dpp_step<0x111, 0xf>(v);  // row_shr:1
    v = dpp_step<0x112, 0xf>(v);  // row_shr:2
    v = dpp_step<0x114, 0xf>(v);  // row_shr:4
    v = dpp_step<0x118, 0xf>(v);  // row_shr:8
    v = dpp_step<0x142, 0xa>(v);  // row_bcast:15 -> rows 1,3
    v = dpp_step<0x143, 0xc>(v);  // row_bcast:31 -> rows 2,3
    return v;
}
__device__ __forceinline__ float lane63(float v) {
    return __int_as_float(__builtin_amdgcn_readlane(__float_as_int(v), 63));
}
__device__ __forceinline__ float rl(float v, int lane) {
    return __int_as_float(__builtin_amdgcn_readlane(__float_as_int(v), lane));
}

// ---------- per-f row statistics of W,b (token-independent) ----------
__global__ void vsn_stats(const float* __restrict__ W, const float* __restrict__ bias,
                          float* __restrict__ stats) {
    const int f = blockIdx.x;
    const int lane = threadIdx.x;
    const float4 w4 = *(const float4*)(W + f * ND + (lane << 2));
    const float4 b4 = *(const float4*)(bias + f * ND + (lane << 2));
    float sw  = (w4.x + w4.y) + (w4.z + w4.w);
    float sb  = (b4.x + b4.y) + (b4.z + b4.w);
    float sww = fmaf(w4.x, w4.x, fmaf(w4.y, w4.y, fmaf(w4.z, w4.z, w4.w * w4.w)));
    float swb = fmaf(w4.x, b4.x, fmaf(w4.y, b4.y, fmaf(w4.z, b4.z, w4.w * b4.w)));
    float sbb = fmaf(b4.x, b4.x, fmaf(b4.y, b4.y, fmaf(b4.z, b4.z, b4.w * b4.w)));
#pragma unroll
    for (int m = 32; m >= 1; m >>= 1) {
        sw += __shfl_xor(sw, m);  sb += __shfl_xor(sb, m);
        sww += __shfl_xor(sww, m); swb += __shfl_xor(swb, m); sbb += __shfl_xor(sbb, m);
    }
    if (lane == 0) {
        const float inv_d = 1.0f / ND;
        stats[f]        = sw * inv_d;
        stats[32 + f]   = sb * inv_d;
        stats[64 + f]   = sww * inv_d;
        stats[96 + f]   = swb * inv_d;
        stats[128 + f]  = sbb * inv_d;
    }
}

// ---------- main kernel: one wave per token, lane l owns d = 4l..4l+3 ----------
// Online-softmax fusion; gelu via LDS Phi-table (1025 nodes over [-8,8],
// linear interp, |err| ~ 2e-4, exact tails h->0 / h->n). No transcendentals
// in the per-element path; only 1 exp2 per f (softmax).
__global__ __launch_bounds__(256, 4) void vsn_kernel(
    const float* __restrict__ x,
    const float* __restrict__ W,
    const float* __restrict__ bias,
    const float* __restrict__ stats,
    const float* __restrict__ ln1g,
    const float* __restrict__ ln1b,
    const float* __restrict__ scw,
    const float* __restrict__ scb,
    const float* __restrict__ outg,
    const float* __restrict__ outb,
    float* __restrict__ out,
    float* __restrict__ wout)
{
    __shared__ float phi[1025];   // Phi((i-512)/64)

    // table init (once per block; erff is OCML-exact, amortized)
    for (int i = threadIdx.x; i < 1025; i += 256)
        phi[i] = 0.5f * (1.0f + erff(((float)i - 512.0f) * 0.011048543456039806f));
    __syncthreads();

    const int lane = threadIdx.x & 63;
    const int wid  = threadIdx.x >> 6;
    const int tok  = (blockIdx.x << 2) | wid;
    const int d0   = lane << 2;
    const int fl   = lane & 31;

    constexpr float inv_d = 1.0f / 256.0f;
    constexpr float LOG2E = 1.4426950408889634f;

    const float xv = x[tok * NF + fl];

    // closed-form LN1 stats for f = fl (no cross-lane reduction)
    const float mu_l  = fmaf(xv, stats[fl], stats[32 + fl]);
    const float ez2   = fmaf(xv * xv, stats[64 + fl],
                             fmaf(xv + xv, stats[96 + fl], stats[128 + fl]));
    const float var_l = fmaf(-mu_l, mu_l, ez2);
    const float rs_l  = rsqrtf(var_l + 1e-5f);

    const float4 g4f  = *(const float4*)(ln1g + d0);
    const float4 b4f  = *(const float4*)(ln1b + d0);
    const float4 sw4f = *(const float4*)(scw + d0);
    const float sbv = scb[0];

    const v2 g01 = {g4f.x, g4f.y},  g23 = {g4f.z, g4f.w};
    const v2 b01 = {b4f.x, b4f.y},  b23 = {b4f.z, b4f.w};

    v2 s01 = {0.f, 0.f}, s23 = {0.f, 0.f};   // sum_f e_f * z[f][d]
    float den = 0.f;
    float epark = 0.f;

#pragma unroll 2
    for (int f = 0; f < NF; ++f) {
        const float xf = rl(xv, f);
        const float mu = rl(mu_l, f);
        const float rs = rl(rs_l, f);
        const v2 xf2 = {xf, xf};
        const v2 mu2 = {mu, mu};
        const v2 rs2 = {rs, rs};

        const float4 w4f = *(const float4*)(W + f * ND + d0);
        const float4 c4f = *(const float4*)(bias + f * ND + d0);
        const v2 w01 = {w4f.x, w4f.y}, w23 = {w4f.z, w4f.w};
        const v2 c01 = {c4f.x, c4f.y}, c23 = {c4f.z, c4f.w};

        const v2 z01 = xf2 * w01 + c01;
        const v2 z23 = xf2 * w23 + c23;

        // n = (z - mu)*rs * g + b
        const v2 n01 = ((z01 - mu2) * rs2) * g01 + b01;
        const v2 n23 = ((z23 - mu2) * rs2) * g23 + b23;

        // table lookup: u = clamp(n*64+512, 0, 1023.99); h = n * lerp(phi)
        const float n0 = n01.x, n1 = n01.y, n2 = n23.x, n3 = n23.y;
        float u0 = fminf(fmaxf(fmaf(n0, 64.0f, 512.0f), 0.0f), 1023.99f);
        float u1 = fminf(fmaxf(fmaf(n1, 64.0f, 512.0f), 0.0f), 1023.99f);
        float u2 = fminf(fmaxf(fmaf(n2, 64.0f, 512.0f), 0.0f), 1023.99f);
        float u3 = fminf(fmaxf(fmaf(n3, 64.0f, 512.0f), 0.0f), 1023.99f);
        const int i0 = (int)u0, i1 = (int)u1, i2 = (int)u2, i3 = (int)u3;
        const float fr0 = u0 - (float)i0, fr1 = u1 - (float)i1;
        const float fr2 = u2 - (float)i2, fr3 = u3 - (float)i3;
        const float p00 = phi[i0], p01 = phi[i0 + 1];
        const float p10 = phi[i1], p11 = phi[i1 + 1];
        const float p20 = phi[i2], p21 = phi[i2 + 1];
        const float p30 = phi[i3], p31 = phi[i3 + 1];
        const float h0 = n0 * fmaf(fr0, p01 - p00, p00);
        const float h1 = n1 * fmaf(fr1, p11 - p10, p10);
        const float h2 = n2 * fmaf(fr2, p21 - p20, p20);
        const float h3 = n3 * fmaf(fr3, p31 - p30, p30);

        const float dp = fmaf(h0, sw4f.x, fmaf(h1, sw4f.y,
                         fmaf(h2, sw4f.z, h3 * sw4f.w)));

        const float sf = lane63(wave_sum63(dp)) + sbv;
        const float e  = EXP2(LOG2E * sf);
        const v2 e2 = {e, e};

        den += e;
        s01 = e2 * z01 + s01;
        s23 = e2 * z23 + s23;
        if (lane == f) epark = e;
    }

    const float invden = __builtin_amdgcn_rcpf(den);

    // selected[d] = S[d]/den ; final LN over selected
    const float v0 = s01.x * invden, v1 = s01.y * invden;
    const float v2e = s23.x * invden, v3 = s23.y * invden;

    const float su = lane63(wave_sum63((v0 + v1) + (v2e + v3)));
    const float qu = lane63(wave_sum63(
        fmaf(v0, v0, fmaf(v1, v1, fmaf(v2e, v2e, v3 * v3)))));
    const float mu  = su * inv_d;
    const float var = fmaf(-mu, mu, qu * inv_d);
    const float rs  = rsqrtf(var + 1e-5f);

    const float4 og4 = *(const float4*)(outg + d0);
    const float4 ob4 = *(const float4*)(outb + d0);
    float4 o;
    o.x = fmaf((v0 - mu) * rs, og4.x, ob4.x);
    o.y = fmaf((v1 - mu) * rs, og4.y, ob4.y);
    o.z = fmaf((v2e - mu) * rs, og4.z, ob4.z);
    o.w = fmaf((v3 - mu) * rs, og4.w, ob4.w);
    *(float4*)(out + tok * ND + d0) = o;

    if (lane < NF) wout[tok * NF + lane] = epark * invden;
}

extern "C" void kernel_launch(void* const* d_in, const int* in_sizes, int n_in,
                              void* d_out, int out_size, void* d_ws, size_t ws_size,
                              hipStream_t stream) {
    const float* x    = (const float*)d_in[0];
    const float* W    = (const float*)d_in[1];
    const float* bias = (const float*)d_in[2];
    const float* ln1g = (const float*)d_in[3];
    const float* ln1b = (const float*)d_in[4];
    const float* scw  = (const float*)d_in[5];
    const float* scb  = (const float*)d_in[6];
    const float* outg = (const float*)d_in[7];
    const float* outb = (const float*)d_in[8];

    float* stats = (float*)d_ws;                 // 5*32 floats
    float* out   = (float*)d_out;                // [NTOK, ND]
    float* wout  = out + (size_t)NTOK * ND;      // [NTOK, NF]

    hipLaunchKernelGGL(vsn_stats, dim3(NF), dim3(64), 0, stream, W, bias, stats);
    hipLaunchKernelGGL(vsn_kernel, dim3(NTOK / 4), dim3(256), 0, stream,
                       x, W, bias, stats, ln1g, ln1b, scw, scb, outg, outb, out, wout);
}

// Round 8
// 68.699 us; speedup vs baseline: 9.9412x; 1.1218x over previous
//
#include <hip/hip_runtime.h>
#include <math.h>

#define NB 8
#define NS 2048
#define NF 32
#define ND 256
#define NTOK (NB * NS)

#define TBL_N 2049              // gelu nodes over [-16,16], step 1/64

typedef float v2f __attribute__((ext_vector_type(2)));

#if __has_builtin(__builtin_amdgcn_exp2f)
#define EXP2(x) __builtin_amdgcn_exp2f(x)
#else
#define EXP2(x) exp2f(x)
#endif

// ---------- DPP wave-sum (64 lanes, result lands in lane 63) ----------
template <int CTRL, int RM>
__device__ __forceinline__ float dpp_step(float v) {
    int t = __builtin_amdgcn_update_dpp(0, __float_as_int(v), CTRL, RM, 0xf, true);
    return v + __int_as_float(t);
}
__device__ __forceinline__ float wave_sum63(float v) {
    v = dpp_step<0x111, 0xf>(v);  // row_shr:1
    v = dpp_step<0x112, 0xf>(v);  // row_shr:2
    v = dpp_step<0x114, 0xf>(v);  // row_shr:4
    v = dpp_step<0x118, 0xf>(v);  // row_shr:8
    v = dpp_step<0x142, 0xa>(v);  // row_bcast:15 -> rows 1,3
    v = dpp_step<0x143, 0xc>(v);  // row_bcast:31 -> rows 2,3
    return v;
}
__device__ __forceinline__ float lane63(float v) {
    return __int_as_float(__builtin_amdgcn_readlane(__float_as_int(v), 63));
}
__device__ __forceinline__ float rl(float v, int lane) {
    return __int_as_float(__builtin_amdgcn_readlane(__float_as_int(v), lane));
}

// ---------- per-f row statistics of W,b (token-independent) ----------
__global__ void vsn_stats(const float* __restrict__ W, const float* __restrict__ bias,
                          float* __restrict__ stats) {
    const int f = blockIdx.x;
    const int lane = threadIdx.x;
    const float4 w4 = *(const float4*)(W + f * ND + (lane << 2));
    const float4 b4 = *(const float4*)(bias + f * ND + (lane << 2));
    float sw  = (w4.x + w4.y) + (w4.z + w4.w);
    float sb  = (b4.x + b4.y) + (b4.z + b4.w);
    float sww = fmaf(w4.x, w4.x, fmaf(w4.y, w4.y, fmaf(w4.z, w4.z, w4.w * w4.w)));
    float swb = fmaf(w4.x, b4.x, fmaf(w4.y, b4.y, fmaf(w4.z, b4.z, w4.w * b4.w)));
    float sbb = fmaf(b4.x, b4.x, fmaf(b4.y, b4.y, fmaf(b4.z, b4.z, b4.w * b4.w)));
#pragma unroll
    for (int m = 32; m >= 1; m >>= 1) {
        sw += __shfl_xor(sw, m);  sb += __shfl_xor(sb, m);
        sww += __shfl_xor(sww, m); swb += __shfl_xor(swb, m); sbb += __shfl_xor(sbb, m);
    }
    if (lane == 0) {
        const float inv_d = 1.0f / ND;
        stats[f]        = sw * inv_d;
        stats[32 + f]   = sb * inv_d;
        stats[64 + f]   = sww * inv_d;
        stats[96 + f]   = swb * inv_d;
        stats[128 + f]  = sbb * inv_d;
    }
}

// ---------- gelu table: {gelu(x_i), gelu(x_{i+1})-gelu(x_i)}, x_i=(i-1024)/64 ----------
__global__ void vsn_table(float2* __restrict__ tbl) {
    const int i = blockIdx.x * 256 + threadIdx.x;
    if (i < TBL_N) {
        const float x0 = ((float)i - 1024.0f) * 0.015625f;
        const float x1 = ((float)(i + 1) - 1024.0f) * 0.015625f;
        const float g0 = 0.5f * x0 * (1.0f + erff(x0 * 0.70710678118654752f));
        const float g1 = 0.5f * x1 * (1.0f + erff(x1 * 0.70710678118654752f));
        tbl[i] = make_float2(g0, g1 - g0);
    }
}

// ---------- main kernel: one wave per token, lane l owns d = 4l..4l+3 ----------
// Online-softmax fusion; gelu via LDS direct-gelu table (lerp, |err|~2.4e-5,
// range [-16,16] covers all possible z-scores exactly). Index computed
// straight from z: u = z*P + Q (LN affine + table scale folded). LOG2E folded
// into score weights (softmax invariant). No transcendentals except 1 exp2/f.
__global__ __launch_bounds__(256, 4) void vsn_kernel(
    const float* __restrict__ x,
    const float* __restrict__ W,
    const float* __restrict__ bias,
    const float* __restrict__ stats,
    const float2* __restrict__ gtbl,
    const float* __restrict__ ln1g,
    const float* __restrict__ ln1b,
    const float* __restrict__ scw,
    const float* __restrict__ scb,
    const float* __restrict__ outg,
    const float* __restrict__ outb,
    float* __restrict__ out,
    float* __restrict__ wout)
{
    __shared__ float2 tab[TBL_N];
    for (int i = threadIdx.x; i < TBL_N; i += 256) tab[i] = gtbl[i];
    __syncthreads();

    const int lane = threadIdx.x & 63;
    const int wid  = threadIdx.x >> 6;
    const int tok  = (blockIdx.x << 2) | wid;
    const int d0   = lane << 2;
    const int fl   = lane & 31;

    constexpr float inv_d = 1.0f / 256.0f;
    constexpr float LOG2E = 1.4426950408889634f;
    const float TBL_MAX = 2047.99f;

    const float xv = x[tok * NF + fl];

    // closed-form LN1 stats for f = fl (no cross-lane reduction)
    const float mu_l  = fmaf(xv, stats[fl], stats[32 + fl]);
    const float ez2   = fmaf(xv * xv, stats[64 + fl],
                             fmaf(xv + xv, stats[96 + fl], stats[128 + fl]));
    const float var_l = fmaf(-mu_l, mu_l, ez2);
    const float rs_l  = rsqrtf(var_l + 1e-5f);

    const float4 g4f  = *(const float4*)(ln1g + d0);
    const float4 b4f  = *(const float4*)(ln1b + d0);
    const float4 sw4f = *(const float4*)(scw + d0);

    // hoisted per-lane constants
    const v2f g64_01 = {g4f.x * 64.0f, g4f.y * 64.0f};
    const v2f g64_23 = {g4f.z * 64.0f, g4f.w * 64.0f};
    const v2f bo_01  = {fmaf(b4f.x, 64.0f, 1024.0f), fmaf(b4f.y, 64.0f, 1024.0f)};
    const v2f bo_23  = {fmaf(b4f.z, 64.0f, 1024.0f), fmaf(b4f.w, 64.0f, 1024.0f)};
    const float q0 = sw4f.x * LOG2E, q1 = sw4f.y * LOG2E;
    const float q2 = sw4f.z * LOG2E, q3 = sw4f.w * LOG2E;
    const float sb2 = scb[0] * LOG2E;

    v2f s01 = {0.f, 0.f}, s23 = {0.f, 0.f};   // sum_f e_f * z[f][d]
    float den = 0.f;
    float epark = 0.f;

#pragma unroll 2
    for (int f = 0; f < NF; ++f) {
        const float xf  = rl(xv, f);
        const float nmu = -rl(mu_l, f);
        const float rs  = rl(rs_l, f);
        const v2f xf2  = {xf, xf};
        const v2f nmu2 = {nmu, nmu};
        const v2f rs2  = {rs, rs};

        const float4 w4f = *(const float4*)(W + f * ND + d0);
        const float4 c4f = *(const float4*)(bias + f * ND + d0);
        const v2f w01 = {w4f.x, w4f.y}, w23 = {w4f.z, w4f.w};
        const v2f c01 = {c4f.x, c4f.y}, c23 = {c4f.z, c4f.w};

        const v2f z01 = xf2 * w01 + c01;
        const v2f z23 = xf2 * w23 + c23;

        // u = z*P + Q : table index units (LN affine + 64x scale + 1024 offset)
        const v2f P01 = rs2 * g64_01;
        const v2f P23 = rs2 * g64_23;
        const v2f Q01 = nmu2 * P01 + bo_01;
        const v2f Q23 = nmu2 * P23 + bo_23;
        const v2f u01 = z01 * P01 + Q01;
        const v2f u23 = z23 * P23 + Q23;

        const float uc0 = __builtin_amdgcn_fmed3f(u01.x, 0.0f, TBL_MAX);
        const float uc1 = __builtin_amdgcn_fmed3f(u01.y, 0.0f, TBL_MAX);
        const float uc2 = __builtin_amdgcn_fmed3f(u23.x, 0.0f, TBL_MAX);
        const float uc3 = __builtin_amdgcn_fmed3f(u23.y, 0.0f, TBL_MAX);
        const int i0 = (int)uc0, i1 = (int)uc1, i2 = (int)uc2, i3 = (int)uc3;
        const float fr0 = uc0 - (float)i0, fr1 = uc1 - (float)i1;
        const float fr2 = uc2 - (float)i2, fr3 = uc3 - (float)i3;
        const float2 t0 = tab[i0], t1 = tab[i1], t2 = tab[i2], t3 = tab[i3];
        const float h0 = fmaf(fr0, t0.y, t0.x);
        const float h1 = fmaf(fr1, t1.y, t1.x);
        const float h2 = fmaf(fr2, t2.y, t2.x);
        const float h3 = fmaf(fr3, t3.y, t3.x);

        // dp already in log2e units (q pre-scaled)
        const float dp = fmaf(h0, q0, fmaf(h1, q1, fmaf(h2, q2, h3 * q3)));

        const float e = EXP2(lane63(wave_sum63(dp)) + sb2);
        const v2f e2 = {e, e};

        den += e;
        s01 = e2 * z01 + s01;
        s23 = e2 * z23 + s23;
        if (lane == f) epark = e;
    }

    const float invden = __builtin_amdgcn_rcpf(den);

    // selected[d] = S[d]/den ; final LN over selected
    const float v0 = s01.x * invden, v1 = s01.y * invden;
    const float v2e = s23.x * invden, v3 = s23.y * invden;

    const float su = lane63(wave_sum63((v0 + v1) + (v2e + v3)));
    const float qu = lane63(wave_sum63(
        fmaf(v0, v0, fmaf(v1, v1, fmaf(v2e, v2e, v3 * v3)))));
    const float mu  = su * inv_d;
    const float var = fmaf(-mu, mu, qu * inv_d);
    const float rs  = rsqrtf(var + 1e-5f);

    const float4 og4 = *(const float4*)(outg + d0);
    const float4 ob4 = *(const float4*)(outb + d0);
    float4 o;
    o.x = fmaf((v0 - mu) * rs, og4.x, ob4.x);
    o.y = fmaf((v1 - mu) * rs, og4.y, ob4.y);
    o.z = fmaf((v2e - mu) * rs, og4.z, ob4.z);
    o.w = fmaf((v3 - mu) * rs, og4.w, ob4.w);
    *(float4*)(out + tok * ND + d0) = o;

    if (lane < NF) wout[tok * NF + lane] = epark * invden;
}

extern "C" void kernel_launch(void* const* d_in, const int* in_sizes, int n_in,
                              void* d_out, int out_size, void* d_ws, size_t ws_size,
                              hipStream_t stream) {
    const float* x    = (const float*)d_in[0];
    const float* W    = (const float*)d_in[1];
    const float* bias = (const float*)d_in[2];
    const float* ln1g = (const float*)d_in[3];
    const float* ln1b = (const float*)d_in[4];
    const float* scw  = (const float*)d_in[5];
    const float* scb  = (const float*)d_in[6];
    const float* outg = (const float*)d_in[7];
    const float* outb = (const float*)d_in[8];

    float*  stats = (float*)d_ws;                          // 160 floats
    float2* tbl   = (float2*)((char*)d_ws + 1024);         // 2049 float2 (16.4 KB)
    float*  out   = (float*)d_out;                         // [NTOK, ND]
    float*  wout  = out + (size_t)NTOK * ND;               // [NTOK, NF]

    hipLaunchKernelGGL(vsn_stats, dim3(NF), dim3(64), 0, stream, W, bias, stats);
    hipLaunchKernelGGL(vsn_table, dim3((TBL_N + 255) / 256), dim3(256), 0, stream, tbl);
    hipLaunchKernelGGL(vsn_kernel, dim3(NTOK / 4), dim3(256), 0, stream,
                       x, W, bias, stats, tbl, ln1g, ln1b, scw, scb, outg, outb, out, wout);
}

// Round 9
// 61.947 us; speedup vs baseline: 11.0247x; 1.1090x over previous
//
#include <hip/hip_runtime.h>
#include <math.h>

#define NB 8
#define NS 2048
#define NF 32
#define ND 256
#define NTOK (NB * NS)

#define TBL_N 2048              // gelu segments over [-16,16], step 1/64

#if __has_builtin(__builtin_amdgcn_exp2f)
#define EXP2(x) __builtin_amdgcn_exp2f(x)
#else
#define EXP2(x) exp2f(x)
#endif

// ---------- DPP wave-sum (64 lanes, result lands in lane 63) ----------
template <int CTRL, int RM>
__device__ __forceinline__ float dpp_step(float v) {
    int t = __builtin_amdgcn_update_dpp(0, __float_as_int(v), CTRL, RM, 0xf, true);
    return v + __int_as_float(t);
}
__device__ __forceinline__ float wave_sum63(float v) {
    v = dpp_step<0x111, 0xf>(v);  // row_shr:1
    v = dpp_step<0x112, 0xf>(v);  // row_shr:2
    v = dpp_step<0x114, 0xf>(v);  // row_shr:4
    v = dpp_step<0x118, 0xf>(v);  // row_shr:8
    v = dpp_step<0x142, 0xa>(v);  // row_bcast:15 -> rows 1,3
    v = dpp_step<0x143, 0xc>(v);  // row_bcast:31 -> rows 2,3
    return v;
}
__device__ __forceinline__ float lane63(float v) {
    return __int_as_float(__builtin_amdgcn_readlane(__float_as_int(v), 63));
}
__device__ __forceinline__ float rl(float v, int lane) {
    return __int_as_float(__builtin_amdgcn_readlane(__float_as_int(v), lane));
}

// ---------- per-f row statistics of W,b (token-independent) ----------
__global__ void vsn_stats(const float* __restrict__ W, const float* __restrict__ bias,
                          float* __restrict__ stats) {
    const int f = blockIdx.x;
    const int lane = threadIdx.x;
    const float4 w4 = *(const float4*)(W + f * ND + (lane << 2));
    const float4 b4 = *(const float4*)(bias + f * ND + (lane << 2));
    float sw  = (w4.x + w4.y) + (w4.z + w4.w);
    float sb  = (b4.x + b4.y) + (b4.z + b4.w);
    float sww = fmaf(w4.x, w4.x, fmaf(w4.y, w4.y, fmaf(w4.z, w4.z, w4.w * w4.w)));
    float swb = fmaf(w4.x, b4.x, fmaf(w4.y, b4.y, fmaf(w4.z, b4.z, w4.w * b4.w)));
    float sbb = fmaf(b4.x, b4.x, fmaf(b4.y, b4.y, fmaf(b4.z, b4.z, b4.w * b4.w)));
#pragma unroll
    for (int m = 32; m >= 1; m >>= 1) {
        sw += __shfl_xor(sw, m);  sb += __shfl_xor(sb, m);
        sww += __shfl_xor(sww, m); swb += __shfl_xor(swb, m); sbb += __shfl_xor(sbb, m);
    }
    if (lane == 0) {
        const float inv_d = 1.0f / ND;
        stats[f]        = sw * inv_d;
        stats[32 + f]   = sb * inv_d;
        stats[64 + f]   = sww * inv_d;
        stats[96 + f]   = swb * inv_d;
        stats[128 + f]  = sbb * inv_d;
    }
}

// ---------- gelu table, slope-intercept in BYTE-index units ----------
// segment i covers byte-index u8 in [8i, 8i+8), x = (i-1024)/64.
// h = a + u8*slope_b  with  slope_b = (g1-g0)/8,  a = g0 - 8i*slope_b.
__global__ void vsn_table(float2* __restrict__ tbl) {
    const int i = blockIdx.x * 256 + threadIdx.x;
    if (i < TBL_N) {
        const float x0 = ((float)i - 1024.0f) * 0.015625f;
        const float x1 = x0 + 0.015625f;
        const float g0 = 0.5f * x0 * (1.0f + erff(x0 * 0.70710678118654752f));
        const float g1 = 0.5f * x1 * (1.0f + erff(x1 * 0.70710678118654752f));
        const float sb = (g1 - g0) * 0.125f;
        const float a  = g0 - (float)(8 * i) * sb;
        tbl[i] = make_float2(a, sb);
    }
}

// ---------- main kernel: one wave per token, lane l owns d = 4l..4l+3 ----------
// Online-softmax fusion; gelu via slope-intercept LDS table indexed in byte
// units straight from z: u8 = (z*rs + t2)*g512 + bo8. No fr/cvt_f32/sub in
// the lerp; den recovered post-loop from epark; scb folded into dot chain.
// All-scalar floats (no ext-vector shuffling).
__global__ __launch_bounds__(256, 4) void vsn_kernel(
    const float* __restrict__ x,
    const float* __restrict__ W,
    const float* __restrict__ bias,
    const float* __restrict__ stats,
    const float2* __restrict__ gtbl,
    const float* __restrict__ ln1g,
    const float* __restrict__ ln1b,
    const float* __restrict__ scw,
    const float* __restrict__ scb,
    const float* __restrict__ outg,
    const float* __restrict__ outb,
    float* __restrict__ out,
    float* __restrict__ wout)
{
    __shared__ float2 tab[TBL_N];
    for (int i = threadIdx.x; i < TBL_N; i += 256) tab[i] = gtbl[i];
    __syncthreads();

    const int lane = threadIdx.x & 63;
    const int wid  = threadIdx.x >> 6;
    const int tok  = (blockIdx.x << 2) | wid;
    const int d0   = lane << 2;
    const int fl   = lane & 31;

    constexpr float inv_d = 1.0f / 256.0f;
    constexpr float LOG2E = 1.4426950408889634f;
    const float TBL_MAX = 16383.0f;

    const float xv = x[tok * NF + fl];

    // closed-form LN1 stats for f = fl (no cross-lane reduction)
    const float mu_l  = fmaf(xv, stats[fl], stats[32 + fl]);
    const float ez2   = fmaf(xv * xv, stats[64 + fl],
                             fmaf(xv + xv, stats[96 + fl], stats[128 + fl]));
    const float var_l = fmaf(-mu_l, mu_l, ez2);
    const float rs_l  = rsqrtf(var_l + 1e-5f);
    const float t2_l  = -mu_l * rs_l;

    const float4 g4f  = *(const float4*)(ln1g + d0);
    const float4 b4f  = *(const float4*)(ln1b + d0);
    const float4 sw4f = *(const float4*)(scw + d0);

    // per-lane constants in byte-index units
    const float ga = g4f.x * 512.0f, gb = g4f.y * 512.0f;
    const float gc = g4f.z * 512.0f, gd = g4f.w * 512.0f;
    const float oa = fmaf(b4f.x, 512.0f, 8192.0f), ob = fmaf(b4f.y, 512.0f, 8192.0f);
    const float oc = fmaf(b4f.z, 512.0f, 8192.0f), od = fmaf(b4f.w, 512.0f, 8192.0f);
    const float q0 = sw4f.x * LOG2E, q1 = sw4f.y * LOG2E;
    const float q2 = sw4f.z * LOG2E, q3 = sw4f.w * LOG2E;
    const float Kv = scb[0] * LOG2E * 0.015625f;   // scb*log2e/64, added per lane

    float s0 = 0.f, s1 = 0.f, s2 = 0.f, s3 = 0.f;
    float epark = 0.f;

#pragma unroll 4
    for (int f = 0; f < NF; ++f) {
        const float xf  = rl(xv, f);
        const float rsf = rl(rs_l, f);
        const float t2f = rl(t2_l, f);

        const float4 w4 = *(const float4*)(W + f * ND + d0);
        const float4 c4 = *(const float4*)(bias + f * ND + d0);

        const float z0 = fmaf(xf, w4.x, c4.x);
        const float z1 = fmaf(xf, w4.y, c4.y);
        const float z2 = fmaf(xf, w4.z, c4.z);
        const float z3 = fmaf(xf, w4.w, c4.w);

        const float t0 = fmaf(z0, rsf, t2f);
        const float t1 = fmaf(z1, rsf, t2f);
        const float t2 = fmaf(z2, rsf, t2f);
        const float t3 = fmaf(z3, rsf, t2f);

        const float u0 = fmaf(t0, ga, oa);
        const float u1 = fmaf(t1, gb, ob);
        const float u2 = fmaf(t2, gc, oc);
        const float u3 = fmaf(t3, gd, od);

        const float uc0 = __builtin_amdgcn_fmed3f(u0, 0.0f, TBL_MAX);
        const float uc1 = __builtin_amdgcn_fmed3f(u1, 0.0f, TBL_MAX);
        const float uc2 = __builtin_amdgcn_fmed3f(u2, 0.0f, TBL_MAX);
        const float uc3 = __builtin_amdgcn_fmed3f(u3, 0.0f, TBL_MAX);

        const int i0 = ((int)uc0) & ~7;
        const int i1 = ((int)uc1) & ~7;
        const int i2 = ((int)uc2) & ~7;
        const int i3 = ((int)uc3) & ~7;

        const float2 T0 = *(const float2*)((const char*)tab + i0);
        const float2 T1 = *(const float2*)((const char*)tab + i1);
        const float2 T2 = *(const float2*)((const char*)tab + i2);
        const float2 T3 = *(const float2*)((const char*)tab + i3);

        const float h0 = fmaf(uc0, T0.y, T0.x);
        const float h1 = fmaf(uc1, T1.y, T1.x);
        const float h2 = fmaf(uc2, T2.y, T2.x);
        const float h3 = fmaf(uc3, T3.y, T3.x);

        const float dp = fmaf(h0, q0, fmaf(h1, q1, fmaf(h2, q2, fmaf(h3, q3, Kv))));

        const float e = EXP2(lane63(wave_sum63(dp)));   // wave-uniform

        epark = (lane == f) ? e : epark;
        s0 = fmaf(e, z0, s0);
        s1 = fmaf(e, z1, s1);
        s2 = fmaf(e, z2, s2);
        s3 = fmaf(e, z3, s3);
    }

    // den = sum_f e_f (epark nonzero only on lanes 0..31)
    const float den = lane63(wave_sum63(epark));
    const float invden = __builtin_amdgcn_rcpf(den);

    const float v0 = s0 * invden, v1 = s1 * invden;
    const float v2 = s2 * invden, v3 = s3 * invden;

    const float su = lane63(wave_sum63((v0 + v1) + (v2 + v3)));
    const float qu = lane63(wave_sum63(
        fmaf(v0, v0, fmaf(v1, v1, fmaf(v2, v2, v3 * v3)))));
    const float mu  = su * inv_d;
    const float var = fmaf(-mu, mu, qu * inv_d);
    const float rso = rsqrtf(var + 1e-5f);

    const float4 og4 = *(const float4*)(outg + d0);
    const float4 ob4 = *(const float4*)(outb + d0);
    float4 o;
    o.x = fmaf((v0 - mu) * rso, og4.x, ob4.x);
    o.y = fmaf((v1 - mu) * rso, og4.y, ob4.y);
    o.z = fmaf((v2 - mu) * rso, og4.z, ob4.z);
    o.w = fmaf((v3 - mu) * rso, og4.w, ob4.w);
    *(float4*)(out + tok * ND + d0) = o;

    if (lane < NF) wout[tok * NF + lane] = epark * invden;
}

extern "C" void kernel_launch(void* const* d_in, const int* in_sizes, int n_in,
                              void* d_out, int out_size, void* d_ws, size_t ws_size,
                              hipStream_t stream) {
    const float* x    = (const float*)d_in[0];
    const float* W    = (const float*)d_in[1];
    const float* bias = (const float*)d_in[2];
    const float* ln1g = (const float*)d_in[3];
    const float* ln1b = (const float*)d_in[4];
    const float* scw  = (const float*)d_in[5];
    const float* scb  = (const float*)d_in[6];
    const float* outg = (const float*)d_in[7];
    const float* outb = (const float*)d_in[8];

    float*  stats = (float*)d_ws;                          // 160 floats
    float2* tbl   = (float2*)((char*)d_ws + 1024);         // 2048 float2 (16 KB)
    float*  out   = (float*)d_out;                         // [NTOK, ND]
    float*  wout  = out + (size_t)NTOK * ND;               // [NTOK, NF]

    hipLaunchKernelGGL(vsn_stats, dim3(NF), dim3(64), 0, stream, W, bias, stats);
    hipLaunchKernelGGL(vsn_table, dim3((TBL_N + 255) / 256), dim3(256), 0, stream, tbl);
    hipLaunchKernelGGL(vsn_kernel, dim3(NTOK / 4), dim3(256), 0, stream,
                       x, W, bias, stats, tbl, ln1g, ln1b, scw, scb, outg, outb, out, wout);
}

// Round 10
// 58.999 us; speedup vs baseline: 11.5755x; 1.0500x over previous
//
#include <hip/hip_runtime.h>
#include <math.h>

#define NB 8
#define NS 2048
#define NF 32
#define ND 256
#define NTOK (NB * NS)

#define TBL_N 2048              // gelu segments over [-16,16], step 1/64

#if __has_builtin(__builtin_amdgcn_exp2f)
#define EXP2(x) __builtin_amdgcn_exp2f(x)
#else
#define EXP2(x) exp2f(x)
#endif

// ---------- DPP partial wave-sum: totals at lane 31 (lanes 0-31) and lane 63
// (lanes 32-63) after 5 steps ----------
template <int CTRL, int RM>
__device__ __forceinline__ float dpp_step(float v) {
    int t = __builtin_amdgcn_update_dpp(0, __float_as_int(v), CTRL, RM, 0xf, true);
    return v + __int_as_float(t);
}
__device__ __forceinline__ float wave_sum_halves(float v) {
    v = dpp_step<0x111, 0xf>(v);  // row_shr:1
    v = dpp_step<0x112, 0xf>(v);  // row_shr:2
    v = dpp_step<0x114, 0xf>(v);  // row_shr:4
    v = dpp_step<0x118, 0xf>(v);  // row_shr:8
    v = dpp_step<0x142, 0xa>(v);  // row_bcast:15 -> rows 1,3
    return v;                     // lane31 = sum(0..31), lane63 = sum(32..63)
}
__device__ __forceinline__ float rl(float v, int lane) {
    return __int_as_float(__builtin_amdgcn_readlane(__float_as_int(v), lane));
}
__device__ __forceinline__ float bp(int byteidx, float v) {
    return __int_as_float(__builtin_amdgcn_ds_bpermute(byteidx, __float_as_int(v)));
}

// ---------- per-f row statistics of W,b (token-independent) ----------
__global__ void vsn_stats(const float* __restrict__ W, const float* __restrict__ bias,
                          float* __restrict__ stats) {
    const int f = blockIdx.x;
    const int lane = threadIdx.x;
    const float4 w4 = *(const float4*)(W + f * ND + (lane << 2));
    const float4 b4 = *(const float4*)(bias + f * ND + (lane << 2));
    float sw  = (w4.x + w4.y) + (w4.z + w4.w);
    float sb  = (b4.x + b4.y) + (b4.z + b4.w);
    float sww = fmaf(w4.x, w4.x, fmaf(w4.y, w4.y, fmaf(w4.z, w4.z, w4.w * w4.w)));
    float swb = fmaf(w4.x, b4.x, fmaf(w4.y, b4.y, fmaf(w4.z, b4.z, w4.w * b4.w)));
    float sbb = fmaf(b4.x, b4.x, fmaf(b4.y, b4.y, fmaf(b4.z, b4.z, b4.w * b4.w)));
#pragma unroll
    for (int m = 32; m >= 1; m >>= 1) {
        sw += __shfl_xor(sw, m);  sb += __shfl_xor(sb, m);
        sww += __shfl_xor(sww, m); swb += __shfl_xor(swb, m); sbb += __shfl_xor(sbb, m);
    }
    if (lane == 0) {
        const float inv_d = 1.0f / ND;
        stats[f]        = sw * inv_d;
        stats[32 + f]   = sb * inv_d;
        stats[64 + f]   = sww * inv_d;
        stats[96 + f]   = swb * inv_d;
        stats[128 + f]  = sbb * inv_d;
    }
}

// ---------- gelu table, slope-intercept in BYTE-index units ----------
__global__ void vsn_table(float2* __restrict__ tbl) {
    const int i = blockIdx.x * 256 + threadIdx.x;
    if (i < TBL_N) {
        const float x0 = ((float)i - 1024.0f) * 0.015625f;
        const float x1 = x0 + 0.015625f;
        const float g0 = 0.5f * x0 * (1.0f + erff(x0 * 0.70710678118654752f));
        const float g1 = 0.5f * x1 * (1.0f + erff(x1 * 0.70710678118654752f));
        const float sb = (g1 - g0) * 0.125f;
        const float a  = g0 - (float)(8 * i) * sb;
        tbl[i] = make_float2(a, sb);
    }
}

// ---------- main kernel: TWO tokens per wave ----------
// lanes 0-31 = token t0, lanes 32-63 = t1; lane owns 8 d's (d = 8*(lane&31)..+7).
// One 5-step DPP reduction + one exp2 serves both tokens per f-iteration.
// Broadcasts via ds_bpermute (per-half source lane), prefetched 1 iter ahead.
__global__ __launch_bounds__(256, 4) void vsn_kernel(
    const float* __restrict__ x,
    const float* __restrict__ W,
    const float* __restrict__ bias,
    const float* __restrict__ stats,
    const float2* __restrict__ gtbl,
    const float* __restrict__ ln1g,
    const float* __restrict__ ln1b,
    const float* __restrict__ scw,
    const float* __restrict__ scb,
    const float* __restrict__ outg,
    const float* __restrict__ outb,
    float* __restrict__ out,
    float* __restrict__ wout)
{
    __shared__ float2 tab[TBL_N];
    for (int i = threadIdx.x; i < TBL_N; i += 256) tab[i] = gtbl[i];
    __syncthreads();

    const int lane = threadIdx.x & 63;
    const int wid  = threadIdx.x >> 6;
    const int hi32 = lane & 32;                       // 0 | 32
    const int dl   = lane & 31;
    const int tok  = (((blockIdx.x << 2) | wid) << 1) | (lane >> 5);
    const int d0   = dl << 3;

    constexpr float inv_d = 1.0f / 256.0f;
    constexpr float LOG2E = 1.4426950408889634f;
    const float TBL_MAX = 16383.0f;

    const float xv = x[tok * NF + dl];

    // closed-form LN1 stats for f = dl of this half's token
    const float mu_l  = fmaf(xv, stats[dl], stats[32 + dl]);
    const float ez2   = fmaf(xv * xv, stats[64 + dl],
                             fmaf(xv + xv, stats[96 + dl], stats[128 + dl]));
    const float var_l = fmaf(-mu_l, mu_l, ez2);
    const float rs_l  = rsqrtf(var_l + 1e-5f);
    const float t2_l  = -mu_l * rs_l;

    // per-lane d-constants (8 each)
    float gg[8], oo[8], qq[8];
    {
        const float4 gA = *(const float4*)(ln1g + d0);
        const float4 gB = *(const float4*)(ln1g + d0 + 4);
        const float4 bA = *(const float4*)(ln1b + d0);
        const float4 bB = *(const float4*)(ln1b + d0 + 4);
        const float4 qA = *(const float4*)(scw + d0);
        const float4 qB = *(const float4*)(scw + d0 + 4);
        gg[0]=gA.x*512.f; gg[1]=gA.y*512.f; gg[2]=gA.z*512.f; gg[3]=gA.w*512.f;
        gg[4]=gB.x*512.f; gg[5]=gB.y*512.f; gg[6]=gB.z*512.f; gg[7]=gB.w*512.f;
        oo[0]=fmaf(bA.x,512.f,8192.f); oo[1]=fmaf(bA.y,512.f,8192.f);
        oo[2]=fmaf(bA.z,512.f,8192.f); oo[3]=fmaf(bA.w,512.f,8192.f);
        oo[4]=fmaf(bB.x,512.f,8192.f); oo[5]=fmaf(bB.y,512.f,8192.f);
        oo[6]=fmaf(bB.z,512.f,8192.f); oo[7]=fmaf(bB.w,512.f,8192.f);
        qq[0]=qA.x*LOG2E; qq[1]=qA.y*LOG2E; qq[2]=qA.z*LOG2E; qq[3]=qA.w*LOG2E;
        qq[4]=qB.x*LOG2E; qq[5]=qB.y*LOG2E; qq[6]=qB.z*LOG2E; qq[7]=qB.w*LOG2E;
    }
    const float Kv = scb[0] * LOG2E * 0.03125f;   // scb*log2e/32 (32 lanes/token)

    float ss[8];
#pragma unroll
    for (int k = 0; k < 8; ++k) ss[k] = 0.f;
    float epark = 0.f;

    // prefetched broadcasts for f=0
    float xf  = bp(hi32 << 2, xv);
    float rsf = bp(hi32 << 2, rs_l);
    float t2f = bp(hi32 << 2, t2_l);

#pragma unroll 2
    for (int f = 0; f < NF; ++f) {
        // prefetch next iteration's broadcasts (wrap harmlessly at f=31)
        const int bn = ((((f + 1) & 31)) | hi32) << 2;
        const float xf_n  = bp(bn, xv);
        const float rsf_n = bp(bn, rs_l);
        const float t2f_n = bp(bn, t2_l);

        const float4 wA = *(const float4*)(W + f * ND + d0);
        const float4 wB = *(const float4*)(W + f * ND + d0 + 4);
        const float4 cA = *(const float4*)(bias + f * ND + d0);
        const float4 cB = *(const float4*)(bias + f * ND + d0 + 4);
        const float wv[8] = {wA.x, wA.y, wA.z, wA.w, wB.x, wB.y, wB.z, wB.w};
        const float cv[8] = {cA.x, cA.y, cA.z, cA.w, cB.x, cB.y, cB.z, cB.w};

        float zz[8], hh[8];
#pragma unroll
        for (int k = 0; k < 8; ++k) {
            const float z = fmaf(xf, wv[k], cv[k]);
            zz[k] = z;
            const float t = fmaf(z, rsf, t2f);
            const float u = fmaf(t, gg[k], oo[k]);
            const float uc = __builtin_amdgcn_fmed3f(u, 0.0f, TBL_MAX);
            const int idx = ((int)uc) & ~7;
            const float2 T = *(const float2*)((const char*)tab + idx);
            hh[k] = fmaf(uc, T.y, T.x);
        }

        float dpA = fmaf(hh[0], qq[0], fmaf(hh[1], qq[1], fmaf(hh[2], qq[2], Kv)));
        float dpB = fmaf(hh[3], qq[3], fmaf(hh[4], qq[4], hh[5] * qq[5]));
        float dpC = fmaf(hh[6], qq[6], hh[7] * qq[7]);
        const float dp = (dpA + dpB) + dpC;

        const float ws = wave_sum_halves(dp);
        const float sa = rl(ws, 31);
        const float sb = rl(ws, 63);
        const float e  = EXP2(hi32 ? sb : sa);

        epark = (dl == f) ? e : epark;
#pragma unroll
        for (int k = 0; k < 8; ++k) ss[k] = fmaf(e, zz[k], ss[k]);

        xf = xf_n; rsf = rsf_n; t2f = t2f_n;
    }

    // den per half
    const float wsd = wave_sum_halves(epark);
    const float den = hi32 ? rl(wsd, 63) : rl(wsd, 31);
    const float invden = __builtin_amdgcn_rcpf(den);

    float vv[8];
    float vsum = 0.f, vsq = 0.f;
#pragma unroll
    for (int k = 0; k < 8; ++k) {
        vv[k] = ss[k] * invden;
        vsum += vv[k];
        vsq = fmaf(vv[k], vv[k], vsq);
    }

    const float wsu = wave_sum_halves(vsum);
    const float su  = hi32 ? rl(wsu, 63) : rl(wsu, 31);
    const float wsq = wave_sum_halves(vsq);
    const float qu  = hi32 ? rl(wsq, 63) : rl(wsq, 31);

    const float mu  = su * inv_d;
    const float var = fmaf(-mu, mu, qu * inv_d);
    const float rso = rsqrtf(var + 1e-5f);

    const float4 ogA = *(const float4*)(outg + d0);
    const float4 ogB = *(const float4*)(outg + d0 + 4);
    const float4 obA = *(const float4*)(outb + d0);
    const float4 obB = *(const float4*)(outb + d0 + 4);
    const float og[8] = {ogA.x, ogA.y, ogA.z, ogA.w, ogB.x, ogB.y, ogB.z, ogB.w};
    const float ob[8] = {obA.x, obA.y, obA.z, obA.w, obB.x, obB.y, obB.z, obB.w};

    float4 oA, oB;
    oA.x = fmaf((vv[0] - mu) * rso, og[0], ob[0]);
    oA.y = fmaf((vv[1] - mu) * rso, og[1], ob[1]);
    oA.z = fmaf((vv[2] - mu) * rso, og[2], ob[2]);
    oA.w = fmaf((vv[3] - mu) * rso, og[3], ob[3]);
    oB.x = fmaf((vv[4] - mu) * rso, og[4], ob[4]);
    oB.y = fmaf((vv[5] - mu) * rso, og[5], ob[5]);
    oB.z = fmaf((vv[6] - mu) * rso, og[6], ob[6]);
    oB.w = fmaf((vv[7] - mu) * rso, og[7], ob[7]);
    *(float4*)(out + tok * ND + d0) = oA;
    *(float4*)(out + tok * ND + d0 + 4) = oB;

    wout[tok * NF + dl] = epark * invden;
}

extern "C" void kernel_launch(void* const* d_in, const int* in_sizes, int n_in,
                              void* d_out, int out_size, void* d_ws, size_t ws_size,
                              hipStream_t stream) {
    const float* x    = (const float*)d_in[0];
    const float* W    = (const float*)d_in[1];
    const float* bias = (const float*)d_in[2];
    const float* ln1g = (const float*)d_in[3];
    const float* ln1b = (const float*)d_in[4];
    const float* scw  = (const float*)d_in[5];
    const float* scb  = (const float*)d_in[6];
    const float* outg = (const float*)d_in[7];
    const float* outb = (const float*)d_in[8];

    float*  stats = (float*)d_ws;                          // 160 floats
    float2* tbl   = (float2*)((char*)d_ws + 1024);         // 2048 float2 (16 KB)
    float*  out   = (float*)d_out;                         // [NTOK, ND]
    float*  wout  = out + (size_t)NTOK * ND;               // [NTOK, NF]

    hipLaunchKernelGGL(vsn_stats, dim3(NF), dim3(64), 0, stream, W, bias, stats);
    hipLaunchKernelGGL(vsn_table, dim3((TBL_N + 255) / 256), dim3(256), 0, stream, tbl);
    hipLaunchKernelGGL(vsn_kernel, dim3(NTOK / 8), dim3(256), 0, stream,
                       x, W, bias, stats, tbl, ln1g, ln1b, scw, scb, outg, outb, out, wout);
}